// Round 1
// baseline (1297.059 us; speedup 1.0000x reference)
//
#include <hip/hip_runtime.h>
#include <hip/hip_bf16.h>

typedef __attribute__((ext_vector_type(4))) float f32x4;
typedef __attribute__((ext_vector_type(8))) short bf16x8;

#define TPB 512
#define RPB 128
#define NSTEP 20

// tanh(u) = 1 - 2/(exp(2u)+1); exact saturation at +-1 for large |u|.
static __device__ __forceinline__ float fast_tanh(float u) {
    float e = __expf(u + u);
    return 1.0f - 2.0f * __builtin_amdgcn_rcpf(e + 1.0f);
}

// Orders same-wave LDS write->read (DS pipe is in-order per wave; the waitcnt
// makes it unconditional) and is a compiler memory fence (blocks reordering).
#define LDS_FENCE() asm volatile("s_waitcnt lgkmcnt(0)" ::: "memory")

__global__ __launch_bounds__(TPB, 2)
void ode_rk4_kernel(const float* __restrict__ xg,
                    const float* __restrict__ W1,
                    const float* __restrict__ b1g,
                    const float* __restrict__ W2,
                    const float* __restrict__ b2g,
                    float* __restrict__ outg)
{
    // W1 fragments: [(ct*2+kt)*64+lane]*8+j  = bf16(W1[32kt+8*(lane>>4)+j][16ct+(lane&15)])
    __shared__ alignas(16) __hip_bfloat16 W1f[16 * 2 * 64 * 8];   // 32 KB
    // W2 fragments: [(ct*8+kt)*64+lane]*8+j  = bf16(W2[32kt+8*(lane>>4)+j][16ct+(lane&15)])
    __shared__ alignas(16) __hip_bfloat16 W2f[4 * 8 * 64 * 8];    // 32 KB
    __shared__ alignas(16) __hip_bfloat16 Ybuf[RPB * 72];         // 18 KB, pad 72 for banks
    __shared__ alignas(16) __hip_bfloat16 Abuf[8 * 16 * 72];      // 18 KB, wave-private strips

    const int tid = threadIdx.x;
    const int w  = tid >> 6;    // wave 0..7 -> rows 16w..16w+15
    const int l  = tid & 63;
    const int hq = l >> 4;      // 0..3
    const int lc = l & 15;

    // ---- stage weights as pre-swizzled B-fragments (once) ----
    for (int i = tid; i < 64 * 256; i += TPB) {       // W1 is [64][256]
        int k = i >> 8, n = i & 255;
        int lane = (((k & 31) >> 3) << 4) | (n & 15);
        int idx = ((((n >> 4) << 1) | (k >> 5)) * 64 + lane) * 8 + (k & 7);
        W1f[idx] = __float2bfloat16(W1[i]);
    }
    for (int i = tid; i < 256 * 64; i += TPB) {       // W2 is [256][64]
        int k = i >> 6, n = i & 63;
        int lane = (((k & 31) >> 3) << 4) | (n & 15);
        int idx = ((((n >> 4) << 3) | (k >> 5)) * 64 + lane) * 8 + (k & 7);
        W2f[idx] = __float2bfloat16(W2[i]);
    }

    // biases straight into registers (broadcast reads, cached)
    float b1v[16], b2v[4];
#pragma unroll
    for (int ct = 0; ct < 16; ++ct) b1v[ct] = b1g[(ct << 4) + lc];
#pragma unroll
    for (int c = 0; c < 4; ++c)     b2v[c]  = b2g[(c << 4) + lc];

    __syncthreads();

    // y state in registers, exactly MFMA C/D layout:
    // y[row = rowbase + r][col = 16c + lc] == y0[c][r]
    const int rowbase = blockIdx.x * RPB + (w << 4) + (hq << 2);
    float y0[4][4];
#pragma unroll
    for (int r = 0; r < 4; ++r)
#pragma unroll
        for (int c = 0; c < 4; ++c)
            y0[c][r] = xg[(rowbase + r) * 64 + (c << 4) + lc];

    __hip_bfloat16* const ybw = &Ybuf[((w << 4) + (hq << 2)) * 72 + lc];
    const __hip_bfloat16* const ybr = &Ybuf[((w << 4) + lc) * 72 + (hq << 3)];
    __hip_bfloat16* const abw = &Abuf[((w << 4) + (hq << 2)) * 72 + lc];
    const __hip_bfloat16* const abr = &Abuf[((w << 4) + lc) * 72 + (hq << 3)];
    const __hip_bfloat16* const w1p = &W1f[l * 8];
    const __hip_bfloat16* const w2p = &W2f[l * 8];

    float kv[4][4];    // f(y) result, D-layout
    float yt[4][4];    // staged argument of next f-eval
    float acc[4][4];   // RK4 running combination

    // write yt -> Ybuf (bf16) in D-layout positions
    auto writeY = [&]() {
#pragma unroll
        for (int r = 0; r < 4; ++r)
#pragma unroll
            for (int c = 0; c < 4; ++c)
                ybw[r * 72 + (c << 4)] = __float2bfloat16(yt[c][r]);
    };

    // kv = f(Ybuf) ; wave-private, fused matmul1 -> tanh -> matmul2
    auto feval = [&]() {
        LDS_FENCE();   // Ybuf writes -> A-frag reads
        bf16x8 aY0 = *reinterpret_cast<const bf16x8*>(ybr);        // k 0..31
        bf16x8 aY1 = *reinterpret_cast<const bf16x8*>(ybr + 32);   // k 32..63
        f32x4 kacc[4];
#pragma unroll
        for (int ct = 0; ct < 4; ++ct) kacc[ct] = (f32x4){0.f, 0.f, 0.f, 0.f};

#pragma unroll
        for (int cc = 0; cc < 4; ++cc) {           // 64-col chunk of hidden dim
#pragma unroll
            for (int t2 = 0; t2 < 4; ++t2) {       // 16-col tiles within chunk
                const int ct = (cc << 2) + t2;
                f32x4 u = (f32x4){0.f, 0.f, 0.f, 0.f};
                bf16x8 bA = *reinterpret_cast<const bf16x8*>(w1p + ((ct << 1)    ) * 512);
                bf16x8 bB = *reinterpret_cast<const bf16x8*>(w1p + (((ct << 1)|1)) * 512);
                u = __builtin_amdgcn_mfma_f32_16x16x32_bf16(aY0, bA, u, 0, 0, 0);
                u = __builtin_amdgcn_mfma_f32_16x16x32_bf16(aY1, bB, u, 0, 0, 0);
#pragma unroll
                for (int r = 0; r < 4; ++r) {
                    float tv = fast_tanh(u[r] + b1v[ct]);
                    abw[r * 72 + (t2 << 4)] = __float2bfloat16(tv);
                }
            }
            LDS_FENCE();   // Abuf writes -> reads
#pragma unroll
            for (int ktl = 0; ktl < 2; ++ktl) {
                bf16x8 aA = *reinterpret_cast<const bf16x8*>(abr + (ktl << 5));
#pragma unroll
                for (int ct = 0; ct < 4; ++ct) {
                    bf16x8 bW = *reinterpret_cast<const bf16x8*>(
                        w2p + ((ct << 3) + (cc << 1) + ktl) * 512);
                    kacc[ct] = __builtin_amdgcn_mfma_f32_16x16x32_bf16(aA, bW, kacc[ct], 0, 0, 0);
                }
            }
            LDS_FENCE();   // Abuf reads -> next chunk's writes (WAR)
        }
#pragma unroll
        for (int ct = 0; ct < 4; ++ct)
#pragma unroll
            for (int r = 0; r < 4; ++r)
                kv[ct][r] = kacc[ct][r] + b2v[ct];
    };

    const float h = 0.05f;

    for (int s = 0; s < NSTEP; ++s) {
#pragma unroll
        for (int c = 0; c < 4; ++c)
#pragma unroll
            for (int r = 0; r < 4; ++r) yt[c][r] = y0[c][r];
        writeY(); feval();                               // k1
#pragma unroll
        for (int c = 0; c < 4; ++c)
#pragma unroll
            for (int r = 0; r < 4; ++r) {
                acc[c][r] = kv[c][r];
                yt[c][r]  = y0[c][r] + 0.5f * h * kv[c][r];
            }
        writeY(); feval();                               // k2
#pragma unroll
        for (int c = 0; c < 4; ++c)
#pragma unroll
            for (int r = 0; r < 4; ++r) {
                acc[c][r] += 2.0f * kv[c][r];
                yt[c][r]   = y0[c][r] + 0.5f * h * kv[c][r];
            }
        writeY(); feval();                               // k3
#pragma unroll
        for (int c = 0; c < 4; ++c)
#pragma unroll
            for (int r = 0; r < 4; ++r) {
                acc[c][r] += 2.0f * kv[c][r];
                yt[c][r]   = y0[c][r] + h * kv[c][r];
            }
        writeY(); feval();                               // k4
#pragma unroll
        for (int c = 0; c < 4; ++c)
#pragma unroll
            for (int r = 0; r < 4; ++r)
                y0[c][r] += (h / 6.0f) * (acc[c][r] + kv[c][r]);
    }

#pragma unroll
    for (int r = 0; r < 4; ++r)
#pragma unroll
        for (int c = 0; c < 4; ++c)
            outg[(rowbase + r) * 64 + (c << 4) + lc] = y0[c][r];
}

extern "C" void kernel_launch(void* const* d_in, const int* in_sizes, int n_in,
                              void* d_out, int out_size, void* d_ws, size_t ws_size,
                              hipStream_t stream) {
    const float* x  = (const float*)d_in[0];
    const float* W1 = (const float*)d_in[1];
    const float* b1 = (const float*)d_in[2];
    const float* W2 = (const float*)d_in[3];
    const float* b2 = (const float*)d_in[4];
    float* out = (float*)d_out;
    ode_rk4_kernel<<<dim3(131072 / RPB), dim3(TPB), 0, stream>>>(x, W1, b1, W2, b2, out);
}

// Round 2
// 954.657 us; speedup vs baseline: 1.3587x; 1.3587x over previous
//
#include <hip/hip_runtime.h>
#include <hip/hip_bf16.h>

typedef __attribute__((ext_vector_type(4))) float f32x4;
typedef __attribute__((ext_vector_type(8))) short bf16x8;
typedef __attribute__((ext_vector_type(2))) unsigned u32x2;

#define TPB 1024
#define RPB 256            // 16 waves * 16 batch rows
#define NSTEP 20
#define SC 2.8853900817779268f   // 2*log2(e), folded into W1 and b1

// Same-wave LDS write->read ordering (DS pipe is in-order per wave; this makes
// the wait unconditional) + compiler memory fence.
#define LDS_FENCE() asm volatile("s_waitcnt lgkmcnt(0)" ::: "memory")

static __device__ __forceinline__ unsigned cvt_pk(float a, float b) {
    unsigned r;
    asm("v_cvt_pk_bf16_f32 %0, %1, %2" : "=v"(r) : "v"(a), "v"(b));
    return r;   // lo = bf16(a), hi = bf16(b)
}

// input already scaled by 2*log2(e): tanh(u) = 1 - 2/(exp2(SC*u)+1)
static __device__ __forceinline__ float tanh_pre(float v) {
    float e = __builtin_amdgcn_exp2f(v);
    return 1.0f - 2.0f * __builtin_amdgcn_rcpf(e + 1.0f);
}

__global__ __launch_bounds__(TPB, 4)
void ode_rk4_kernel(const float* __restrict__ xg,
                    const float* __restrict__ W1g,
                    const float* __restrict__ b1g,
                    const float* __restrict__ W2g,
                    const float* __restrict__ b2g,
                    float* __restrict__ outg)
{
    // Transposed scheme: state z = y^T held in D-layout registers.
    // W1 A-frags (t,kt): lane l holds W1[32kt+8(l>>4)+j][16t+(l&15)] * SC
    __shared__ alignas(16) __hip_bfloat16 W1f[32 * 512];          // 32 KB
    // W2 A-frags (c,kt): lane l holds W2[32kt+8(l>>4)+j][16c+(l&15)]
    __shared__ alignas(16) __hip_bfloat16 W2f[32 * 512];          // 32 KB
    __shared__ alignas(16) float          b1f[16 * 256];          // 16 KB  [t][l][r] = SC*b1[16t+4(l>>4)+r]
    __shared__ alignas(16) float          b2f[4 * 256];           //  4 KB  [c][l][r] = b2[16c+4(l>>4)+r]
    __shared__ alignas(16) __hip_bfloat16 Ybuf[16 * 16 * 72];     // 36 KB  per-wave [16 batch][72]
    __shared__ alignas(16) __hip_bfloat16 Abuf[16 * 16 * 72];     // 36 KB  per-wave strip (64-hid chunk)

    const int tid = threadIdx.x;
    const int w  = tid >> 6;
    const int l  = tid & 63;
    const int hq = l >> 4;
    const int lc = l & 15;

    // ---- stage weights/biases as MFMA fragments (once per block) ----
    for (int i = tid; i < 16384; i += TPB) {                 // W1 [64][256]
        int f = i >> 8, hcol = i & 255;
        int idx = ((((hcol >> 4) << 1) | (f >> 5)) * 64 + (((f >> 3) & 3) << 4) + (hcol & 15)) * 8 + (f & 7);
        W1f[idx] = __float2bfloat16(W1g[i] * SC);
    }
    for (int i = tid; i < 16384; i += TPB) {                 // W2 [256][64]
        int hrow = i >> 6, d = i & 63;
        int idx = ((((d >> 4) << 3) | (hrow >> 5)) * 64 + (((hrow >> 3) & 3) << 4) + (d & 15)) * 8 + (hrow & 7);
        W2f[idx] = __float2bfloat16(W2g[i]);
    }
    for (int i = tid; i < 4096; i += TPB) {
        int t = i >> 8, l2 = (i >> 2) & 63, r = i & 3;
        b1f[i] = b1g[(t << 4) + ((l2 >> 4) << 2) + r] * SC;
    }
    for (int i = tid; i < 1024; i += TPB) {
        int c = i >> 8, l2 = (i >> 2) & 63, r = i & 3;
        b2f[i] = b2g[(c << 4) + ((l2 >> 4) << 2) + r];
    }
    __syncthreads();

    // state: zs[c][r] = y[batch lc][feature 16c+4hq+r]   (D-layout of y^T)
    const long rowbase = (long)blockIdx.x * RPB + (w << 4) + lc;
    const float* xrow = xg + rowbase * 64;
    f32x4 zs[4];
#pragma unroll
    for (int c = 0; c < 4; ++c)
        zs[c] = *reinterpret_cast<const f32x4*>(xrow + (c << 4) + (hq << 2));

    __hip_bfloat16* const ybw = &Ybuf[(w * 16 + lc) * 72 + (hq << 2)];
    const __hip_bfloat16* const ybr = &Ybuf[(w * 16 + lc) * 72 + (hq << 3)];
    __hip_bfloat16* const abw = &Abuf[(w * 16 + lc) * 72 + (hq << 2)];
    const __hip_bfloat16* const abr = &Abuf[(w * 16 + lc) * 72 + (hq << 3)];
    const __hip_bfloat16* const w1p = &W1f[l * 8];
    const __hip_bfloat16* const w2p = &W2f[l * 8];
    const f32x4* const b1p = reinterpret_cast<const f32x4*>(&b1f[l * 4]);
    const f32x4* const b2p = reinterpret_cast<const f32x4*>(&b2f[l * 4]);

    // write yt (f32, state layout) -> Ybuf bf16 [batch lc][feature]
    auto writeY = [&](const f32x4 yt[4]) {
#pragma unroll
        for (int c = 0; c < 4; ++c) {
            u32x2 p;
            p[0] = cvt_pk(yt[c][0], yt[c][1]);
            p[1] = cvt_pk(yt[c][2], yt[c][3]);
            *reinterpret_cast<u32x2*>(ybw + (c << 4)) = p;
        }
    };

    // kv = f(Ybuf)^T in state layout; wave-private
    auto feval = [&](f32x4 kv[4]) {
        LDS_FENCE();   // writeY stores -> B-frag reads
        bf16x8 yB0 = *reinterpret_cast<const bf16x8*>(ybr);        // feat 0..31
        bf16x8 yB1 = *reinterpret_cast<const bf16x8*>(ybr + 32);   // feat 32..63
#pragma unroll
        for (int c = 0; c < 4; ++c) kv[c] = b2p[c * 64];           // C-init = b2
#pragma unroll
        for (int cc = 0; cc < 4; ++cc) {                           // 64-hid chunk
#pragma unroll
            for (int t2 = 0; t2 < 4; ++t2) {
                const int t = (cc << 2) | t2;
                f32x4 u = b1p[t * 64];                             // C-init = SC*b1
                bf16x8 wa0 = *reinterpret_cast<const bf16x8*>(w1p + (t << 10));
                bf16x8 wa1 = *reinterpret_cast<const bf16x8*>(w1p + (t << 10) + 512);
                u = __builtin_amdgcn_mfma_f32_16x16x32_bf16(wa0, yB0, u, 0, 0, 0);
                u = __builtin_amdgcn_mfma_f32_16x16x32_bf16(wa1, yB1, u, 0, 0, 0);
                u32x2 p;
                p[0] = cvt_pk(tanh_pre(u[0]), tanh_pre(u[1]));
                p[1] = cvt_pk(tanh_pre(u[2]), tanh_pre(u[3]));
                *reinterpret_cast<u32x2*>(abw + (t2 << 4)) = p;    // a[lc][16t2+4hq..+3]
            }
            LDS_FENCE();   // Abuf stores -> B-frag reads (WAR vs next chunk: DS in-order)
#pragma unroll
            for (int ktl = 0; ktl < 2; ++ktl) {
                bf16x8 aB = *reinterpret_cast<const bf16x8*>(abr + (ktl << 5));
                const int kt = (cc << 1) | ktl;
#pragma unroll
                for (int c = 0; c < 4; ++c) {
                    bf16x8 wb = *reinterpret_cast<const bf16x8*>(w2p + (((c << 3) | kt) << 9));
                    kv[c] = __builtin_amdgcn_mfma_f32_16x16x32_bf16(wb, aB, kv[c], 0, 0, 0);
                }
            }
        }
    };

    const float h = 0.05f;
    f32x4 kv[4], acc[4], yt[4];

#pragma unroll 1
    for (int s = 0; s < NSTEP; ++s) {
        writeY(zs); feval(kv);                                   // k1
#pragma unroll
        for (int c = 0; c < 4; ++c) {
            acc[c] = kv[c];
            yt[c]  = zs[c] + (0.5f * h) * kv[c];
        }
        writeY(yt); feval(kv);                                   // k2
#pragma unroll
        for (int c = 0; c < 4; ++c) {
            acc[c] += 2.0f * kv[c];
            yt[c]   = zs[c] + (0.5f * h) * kv[c];
        }
        writeY(yt); feval(kv);                                   // k3
#pragma unroll
        for (int c = 0; c < 4; ++c) {
            acc[c] += 2.0f * kv[c];
            yt[c]   = zs[c] + h * kv[c];
        }
        writeY(yt); feval(kv);                                   // k4
#pragma unroll
        for (int c = 0; c < 4; ++c)
            zs[c] += (h / 6.0f) * (acc[c] + kv[c]);
    }

    float* orow = outg + rowbase * 64;
#pragma unroll
    for (int c = 0; c < 4; ++c)
        *reinterpret_cast<f32x4*>(orow + (c << 4) + (hq << 2)) = zs[c];
}

extern "C" void kernel_launch(void* const* d_in, const int* in_sizes, int n_in,
                              void* d_out, int out_size, void* d_ws, size_t ws_size,
                              hipStream_t stream) {
    const float* x  = (const float*)d_in[0];
    const float* W1 = (const float*)d_in[1];
    const float* b1 = (const float*)d_in[2];
    const float* W2 = (const float*)d_in[3];
    const float* b2 = (const float*)d_in[4];
    float* out = (float*)d_out;
    ode_rk4_kernel<<<dim3(131072 / RPB), dim3(TPB), 0, stream>>>(x, W1, b1, W2, b2, out);
}

// Round 3
// 807.165 us; speedup vs baseline: 1.6069x; 1.1827x over previous
//
#include <hip/hip_runtime.h>
#include <hip/hip_bf16.h>

typedef __attribute__((ext_vector_type(4))) float f32x4;
typedef __attribute__((ext_vector_type(8))) short bf16x8;
typedef __attribute__((ext_vector_type(2))) unsigned u32x2;
typedef __attribute__((ext_vector_type(4))) unsigned u32x4;

#define TPB 512
#define RPB 256            // 8 waves * 32 rows
#define NSTEP 20
#define SC 2.8853900817779268f   // 2*log2(e), folded into W1 and b1

static __device__ __forceinline__ unsigned cvt_pk(float a, float b) {
    unsigned r;
    asm("v_cvt_pk_bf16_f32 %0, %1, %2" : "=v"(r) : "v"(a), "v"(b));
    return r;   // lo = bf16(a), hi = bf16(b)
}
// input pre-scaled by 2*log2(e): tanh(u) = 1 - 2/(exp2(v)+1)
static __device__ __forceinline__ float tanh_pre(float v) {
    float e = __builtin_amdgcn_exp2f(v);
    return 1.0f - 2.0f * __builtin_amdgcn_rcpf(e + 1.0f);
}
static __device__ __forceinline__ f32x4 unpack4(u32x2 p) {   // 4 bf16 -> 4 f32
    f32x4 r;
    r[0] = __builtin_bit_cast(float, p[0] << 16);
    r[1] = __builtin_bit_cast(float, p[0] & 0xFFFF0000u);
    r[2] = __builtin_bit_cast(float, p[1] << 16);
    r[3] = __builtin_bit_cast(float, p[1] & 0xFFFF0000u);
    return r;
}
static __device__ __forceinline__ bf16x8 pack8(f32x4 p, f32x4 q) {
    u32x4 t;
    t[0] = cvt_pk(p[0], p[1]); t[1] = cvt_pk(p[2], p[3]);
    t[2] = cvt_pk(q[0], q[1]); t[3] = cvt_pk(q[2], q[3]);
    return __builtin_bit_cast(bf16x8, t);
}

// Fragment enumeration trick: hid index kappa(32kt+8hq+j) = 32kt+16(j>>2)+4hq+(j&3)
// makes matmul1's D registers (tiles 2kt,2kt+1, regs j&3) exactly matmul2's
// B-fragment for k-window kt -> activations never touch LDS. Same for feature
// dim chaining matmul2's D back to matmul1's B (y). Weights staged permuted.

__global__ __launch_bounds__(TPB, 2)
void ode_rk4_kernel(const float* __restrict__ xg,
                    const float* __restrict__ W1g,
                    const float* __restrict__ b1g,
                    const float* __restrict__ W2g,
                    const float* __restrict__ b2g,
                    float* __restrict__ outg)
{
    __shared__ alignas(16) __hip_bfloat16 W1f[32 * 512];   // 32 KB  frag (t*2+ktw)
    __shared__ alignas(16) __hip_bfloat16 W2f[32 * 512];   // 32 KB  frag (c*8+kt)
    __shared__ alignas(16) __hip_bfloat16 b1f[16 * 256];   //  8 KB  [t][lane][r]
    __shared__ alignas(16) __hip_bfloat16 b2f[4 * 256];    //  2 KB  [c][lane][r]

    const int tid = threadIdx.x;
    const int w  = tid >> 6;
    const int l  = tid & 63;
    const int hq = l >> 4;

    // ---- stage permuted weight fragments (once per block) ----
    for (int i = tid; i < 16384; i += TPB) {               // W1 [64][256]
        int f = i >> 8, hcol = i & 255;
        int ktw = f >> 5, v = f & 31;
        int hqa = (v >> 2) & 3, ja = ((v >> 4) << 2) | (v & 3);
        int t = hcol >> 4, lca = hcol & 15;
        W1f[(((t << 1) | ktw) * 64 + (hqa << 4) + lca) * 8 + ja] =
            __float2bfloat16(W1g[i] * SC);
    }
    for (int i = tid; i < 16384; i += TPB) {               // W2 [256][64]
        int hrow = i >> 6, d = i & 63;
        int kt = hrow >> 5, v = hrow & 31;
        int hqa = (v >> 2) & 3, ja = ((v >> 4) << 2) | (v & 3);
        int c = d >> 4, lca = d & 15;
        W2f[(((c << 3) | kt) * 64 + (hqa << 4) + lca) * 8 + ja] =
            __float2bfloat16(W2g[i]);
    }
    for (int i = tid; i < 4096; i += TPB) {
        int t = i >> 8, l2 = (i >> 2) & 63, r = i & 3;
        b1f[i] = __float2bfloat16(b1g[(t << 4) + ((l2 >> 4) << 2) + r] * SC);
    }
    for (int i = tid; i < 1024; i += TPB) {
        int c = i >> 8, l2 = (i >> 2) & 63, r = i & 3;
        b2f[i] = __float2bfloat16(b2g[(c << 4) + ((l2 >> 4) << 2) + r]);
    }
    __syncthreads();

    const __hip_bfloat16* const w1p = &W1f[l * 8];
    const __hip_bfloat16* const w2p = &W2f[l * 8];
    const __hip_bfloat16* const b1p = &b1f[l * 4];
    const __hip_bfloat16* const b2p = &b2f[l * 4];

    // state zs[bt][c][r] = y[row_bt][feature 16c+4hq+r]  (MFMA D layout)
    f32x4 zs[2][4], acc[2][4], kacc[2][4];
    bf16x8 yB[2][2];

    long row0[2];
#pragma unroll
    for (int bt = 0; bt < 2; ++bt) {
        row0[bt] = (long)blockIdx.x * RPB + (w << 5) + (bt << 4) + (l & 15);
        const float* xr = xg + row0[bt] * 64 + (hq << 2);
#pragma unroll
        for (int c = 0; c < 4; ++c)
            zs[bt][c] = *reinterpret_cast<const f32x4*>(xr + (c << 4));
    }

    // kacc[bt] = f(yB[bt]) + b2 ; all activations register-resident
    auto feval = [&]() {
#pragma unroll
        for (int c = 0; c < 4; ++c) {
            f32x4 b2v = unpack4(*reinterpret_cast<const u32x2*>(b2p + (c << 8)));
            kacc[0][c] = b2v; kacc[1][c] = b2v;
        }
#pragma unroll
        for (int tt = 0; tt < 8; ++tt) {
            bf16x8 wa0 = *reinterpret_cast<const bf16x8*>(w1p + (((tt << 2) | 0) << 9));
            bf16x8 wa1 = *reinterpret_cast<const bf16x8*>(w1p + (((tt << 2) | 1) << 9));
            bf16x8 wa2 = *reinterpret_cast<const bf16x8*>(w1p + (((tt << 2) | 2) << 9));
            bf16x8 wa3 = *reinterpret_cast<const bf16x8*>(w1p + (((tt << 2) | 3) << 9));
            f32x4 c0 = unpack4(*reinterpret_cast<const u32x2*>(b1p + (tt << 9)));
            f32x4 c1 = unpack4(*reinterpret_cast<const u32x2*>(b1p + (tt << 9) + 256));
            bf16x8 wb0 = *reinterpret_cast<const bf16x8*>(w2p + ((( 0 << 3) | tt) << 9));
            bf16x8 wb1 = *reinterpret_cast<const bf16x8*>(w2p + ((( 1 << 3) | tt) << 9));
            bf16x8 wb2 = *reinterpret_cast<const bf16x8*>(w2p + ((( 2 << 3) | tt) << 9));
            bf16x8 wb3 = *reinterpret_cast<const bf16x8*>(w2p + ((( 3 << 3) | tt) << 9));
#pragma unroll
            for (int bt = 0; bt < 2; ++bt) {
                f32x4 u0 = c0, u1 = c1;
                u0 = __builtin_amdgcn_mfma_f32_16x16x32_bf16(wa0, yB[bt][0], u0, 0, 0, 0);
                u0 = __builtin_amdgcn_mfma_f32_16x16x32_bf16(wa1, yB[bt][1], u0, 0, 0, 0);
                u1 = __builtin_amdgcn_mfma_f32_16x16x32_bf16(wa2, yB[bt][0], u1, 0, 0, 0);
                u1 = __builtin_amdgcn_mfma_f32_16x16x32_bf16(wa3, yB[bt][1], u1, 0, 0, 0);
                f32x4 a0, a1;
#pragma unroll
                for (int r = 0; r < 4; ++r) { a0[r] = tanh_pre(u0[r]); a1[r] = tanh_pre(u1[r]); }
                bf16x8 aB = pack8(a0, a1);
                kacc[bt][0] = __builtin_amdgcn_mfma_f32_16x16x32_bf16(wb0, aB, kacc[bt][0], 0, 0, 0);
                kacc[bt][1] = __builtin_amdgcn_mfma_f32_16x16x32_bf16(wb1, aB, kacc[bt][1], 0, 0, 0);
                kacc[bt][2] = __builtin_amdgcn_mfma_f32_16x16x32_bf16(wb2, aB, kacc[bt][2], 0, 0, 0);
                kacc[bt][3] = __builtin_amdgcn_mfma_f32_16x16x32_bf16(wb3, aB, kacc[bt][3], 0, 0, 0);
            }
        }
    };

    const float h = 0.05f;

#pragma unroll 1
    for (int s = 0; s < NSTEP; ++s) {
#pragma unroll
        for (int bt = 0; bt < 2; ++bt) {
            yB[bt][0] = pack8(zs[bt][0], zs[bt][1]);
            yB[bt][1] = pack8(zs[bt][2], zs[bt][3]);
#pragma unroll
            for (int c = 0; c < 4; ++c) acc[bt][c] = (f32x4){0.f, 0.f, 0.f, 0.f};
        }
#pragma unroll 1
        for (int st = 0; st < 4; ++st) {
            feval();
            const float wv = (st == 1 || st == 2) ? 2.0f : 1.0f;
#pragma unroll
            for (int bt = 0; bt < 2; ++bt)
#pragma unroll
                for (int c = 0; c < 4; ++c)
                    acc[bt][c] += wv * kacc[bt][c];
            if (st < 3) {
                const float av = (st == 2) ? h : 0.5f * h;
#pragma unroll
                for (int bt = 0; bt < 2; ++bt) {
                    f32x4 y0 = zs[bt][0] + av * kacc[bt][0];
                    f32x4 y1 = zs[bt][1] + av * kacc[bt][1];
                    f32x4 y2 = zs[bt][2] + av * kacc[bt][2];
                    f32x4 y3 = zs[bt][3] + av * kacc[bt][3];
                    yB[bt][0] = pack8(y0, y1);
                    yB[bt][1] = pack8(y2, y3);
                }
            }
        }
#pragma unroll
        for (int bt = 0; bt < 2; ++bt)
#pragma unroll
            for (int c = 0; c < 4; ++c)
                zs[bt][c] += (h / 6.0f) * acc[bt][c];
    }

#pragma unroll
    for (int bt = 0; bt < 2; ++bt) {
        float* orow = outg + row0[bt] * 64 + (hq << 2);
#pragma unroll
        for (int c = 0; c < 4; ++c)
            *reinterpret_cast<f32x4*>(orow + (c << 4)) = zs[bt][c];
    }
}

extern "C" void kernel_launch(void* const* d_in, const int* in_sizes, int n_in,
                              void* d_out, int out_size, void* d_ws, size_t ws_size,
                              hipStream_t stream) {
    const float* x  = (const float*)d_in[0];
    const float* W1 = (const float*)d_in[1];
    const float* b1 = (const float*)d_in[2];
    const float* W2 = (const float*)d_in[3];
    const float* b2 = (const float*)d_in[4];
    float* out = (float*)d_out;
    ode_rk4_kernel<<<dim3(131072 / RPB), dim3(TPB), 0, stream>>>(x, W1, b1, W2, b2, out);
}